// Round 6
// baseline (241.862 us; speedup 1.0000x reference)
//
#include <hip/hip_runtime.h>
#include <math.h>

#define N_NODES 50000
#define N_EDGES 800000
#define NFEAT 128
#define NHID 64
#define NCLASS 40
#define LN_EPS 1e-5f
#define NPB 32          // nodes per aggregation block
#define H2ROWS 64       // rows per h2mm block

__device__ __forceinline__ int swz(int k) { return ((k >> 2) & 7) << 2; }

// pack two f32 -> two bf16 (RNE) in one uint
__device__ __forceinline__ unsigned packbf(float a, float b) {
  unsigned ua = __float_as_uint(a), ub = __float_as_uint(b);
  ua += 0x7fffu + ((ua >> 16) & 1u);
  ub += 0x7fffu + ((ub >> 16) & 1u);
  return (ua >> 16) | (ub & 0xffff0000u);
}
__device__ __forceinline__ unsigned bf16hi(float a) {  // bf16(a) in top 16 bits
  unsigned u = __float_as_uint(a);
  u += 0x7fffu + ((u >> 16) & 1u);
  return u & 0xffff0000u;
}
__device__ __forceinline__ float lo16(unsigned v) { return __uint_as_float(v << 16); }
__device__ __forceinline__ float hi16(unsigned v) { return __uint_as_float(v & 0xffff0000u); }

// ------ Kernel A: h1 = x @ W1 (reg-blocked 4x4) + fused s_src/s_dst ------------
__global__ __launch_bounds__(256) void k_h1mm(const float* __restrict__ x,
    const float* __restrict__ W1, const float* __restrict__ a1,
    unsigned* __restrict__ h1u, float* __restrict__ s_src, float* __restrict__ s_dst) {
  __shared__ float xT[NFEAT * 64];    // 32 KB
  __shared__ float W1s[NFEAT * NHID]; // 32 KB
  int t = threadIdx.x;
  int R0 = blockIdx.x * 64;
  for (int i = t; i < NFEAT * NHID / 4; i += 256)
    ((float4*)W1s)[i] = ((const float4*)W1)[i];
#pragma unroll
  for (int it = 0; it < 8; ++it) {
    int i = t + it * 256;
    int r = i >> 5, kq = i & 31;
    int gr = R0 + r;
    float4 v = make_float4(0.f, 0.f, 0.f, 0.f);
    if (gr < N_NODES) v = *(const float4*)(x + (size_t)gr * NFEAT + kq * 4);
    int rw = r ^ ((kq & 7) << 2);
    xT[(kq * 4 + 0) * 64 + rw] = v.x;
    xT[(kq * 4 + 1) * 64 + rw] = v.y;
    xT[(kq * 4 + 2) * 64 + rw] = v.z;
    xT[(kq * 4 + 3) * 64 + rw] = v.w;
  }
  __syncthreads();
  int cg = t & 15, rg = t >> 4;
  int c0 = cg * 4, r0 = rg * 4;
  float acc[4][4] = {};
#pragma unroll 4
  for (int k = 0; k < NFEAT; ++k) {
    float4 xv = *(const float4*)&xT[k * 64 + (r0 ^ swz(k))];
    float4 wv = *(const float4*)&W1s[k * NHID + c0];
    float xr[4] = {xv.x, xv.y, xv.z, xv.w};
    float wr[4] = {wv.x, wv.y, wv.z, wv.w};
#pragma unroll
    for (int j = 0; j < 4; ++j)
#pragma unroll
      for (int c = 0; c < 4; ++c)
        acc[j][c] = fmaf(xr[j], wr[c], acc[j][c]);
  }
  float4 as = *(const float4*)(a1 + c0);
  float4 ad = *(const float4*)(a1 + NHID + c0);
  float asr[4] = {as.x, as.y, as.z, as.w};
  float adr[4] = {ad.x, ad.y, ad.z, ad.w};
  float ps[4], pd[4];
#pragma unroll
  for (int j = 0; j < 4; ++j) {
    int gr = R0 + r0 + j;
    if (gr < N_NODES) {
      uint2 pk;
      pk.x = packbf(acc[j][0], acc[j][1]);
      pk.y = packbf(acc[j][2], acc[j][3]);
      *(uint2*)&h1u[(size_t)gr * 32 + (c0 >> 1)] = pk;
    }
    float s = 0.f, d = 0.f;
#pragma unroll
    for (int c = 0; c < 4; ++c) {
      s = fmaf(acc[j][c], asr[c], s);
      d = fmaf(acc[j][c], adr[c], d);
    }
    ps[j] = s; pd[j] = d;
  }
#pragma unroll
  for (int j = 0; j < 4; ++j)
#pragma unroll
    for (int off = 1; off < 16; off <<= 1) {
      ps[j] += __shfl_xor(ps[j], off);
      pd[j] += __shfl_xor(pd[j], off);
    }
  if (cg == 0) {
#pragma unroll
    for (int j = 0; j < 4; ++j) {
      int gr = R0 + r0 + j;
      if (gr < N_NODES) { s_src[gr] = ps[j]; s_dst[gr] = pd[j]; }
    }
  }
}

// ------ Kernel R: res = x @ res_w^T + res_b (reg-blocked 4x5, f32) -------------
__global__ __launch_bounds__(256) void k_resmm(const float* __restrict__ x,
    const float* __restrict__ res_w, const float* __restrict__ res_b,
    float* __restrict__ res) {
  __shared__ float xT[NFEAT * 128];     // 64 KB
  __shared__ float rwT[NFEAT * NCLASS]; // 20 KB
  int t = threadIdx.x;
  int R0 = blockIdx.x * 128;
  for (int i = t; i < NCLASS * NFEAT; i += 256) {
    int c = i / NFEAT, k = i % NFEAT;
    rwT[k * NCLASS + c] = res_w[i];
  }
#pragma unroll
  for (int it = 0; it < 16; ++it) {
    int i = t + it * 256;
    int r = i >> 5, kq = i & 31;
    int gr = R0 + r;
    float4 v = make_float4(0.f, 0.f, 0.f, 0.f);
    if (gr < N_NODES) v = *(const float4*)(x + (size_t)gr * NFEAT + kq * 4);
    int rw = r ^ ((kq & 7) << 2);
    xT[(kq * 4 + 0) * 128 + rw] = v.x;
    xT[(kq * 4 + 1) * 128 + rw] = v.y;
    xT[(kq * 4 + 2) * 128 + rw] = v.z;
    xT[(kq * 4 + 3) * 128 + rw] = v.w;
  }
  __syncthreads();
  int cg = t & 7, rg = t >> 3;
  int c0 = cg * 5, r0 = rg * 4;
  float acc[4][5] = {};
#pragma unroll 4
  for (int k = 0; k < NFEAT; ++k) {
    float4 xv = *(const float4*)&xT[k * 128 + (r0 ^ swz(k))];
    float xr[4] = {xv.x, xv.y, xv.z, xv.w};
    float wr[5];
#pragma unroll
    for (int c = 0; c < 5; ++c) wr[c] = rwT[k * NCLASS + c0 + c];
#pragma unroll
    for (int j = 0; j < 4; ++j)
#pragma unroll
      for (int c = 0; c < 5; ++c)
        acc[j][c] = fmaf(xr[j], wr[c], acc[j][c]);
  }
  float bb[5];
#pragma unroll
  for (int c = 0; c < 5; ++c) bb[c] = res_b[c0 + c];
#pragma unroll
  for (int j = 0; j < 4; ++j) {
    int gr = R0 + r0 + j;
    if (gr < N_NODES) {
#pragma unroll
      for (int c = 0; c < 5; ++c)
        res[(size_t)gr * NCLASS + c0 + c] = acc[j][c] + bb[c];
    }
  }
}

// ---------------- Kernel B: row histogram only ---------------------------------
__global__ __launch_bounds__(256) void k_hist(const int* __restrict__ ei,
    int* __restrict__ cnt) {
  int e = blockIdx.x * 256 + threadIdx.x;
  if (e >= N_EDGES) return;
  atomicAdd(&cnt[ei[e]], 1);
}

// ---------------- Scan (3 kernels): exclusive prefix over cnt -> row_ptr -------
__global__ __launch_bounds__(256) void k_scan1(const int* __restrict__ cnt,
    int* __restrict__ excl, int* __restrict__ bsum) {
  __shared__ int sd[256];
  int t = threadIdx.x;
  int i = blockIdx.x * 256 + t;
  int v = (i < N_NODES) ? cnt[i] : 0;
  sd[t] = v;
  __syncthreads();
#pragma unroll
  for (int off = 1; off < 256; off <<= 1) {
    int a = (t >= off) ? sd[t - off] : 0;
    __syncthreads();
    sd[t] += a;
    __syncthreads();
  }
  if (i < N_NODES) excl[i] = sd[t] - v;
  if (t == 255) bsum[blockIdx.x] = sd[255];
}

__global__ __launch_bounds__(256) void k_scan2(const int* __restrict__ bsum,
    int* __restrict__ boff, int nb, int* __restrict__ row_ptr_end) {
  __shared__ int sd[256];
  int t = threadIdx.x;
  int v = (t < nb) ? bsum[t] : 0;
  sd[t] = v;
  __syncthreads();
#pragma unroll
  for (int off = 1; off < 256; off <<= 1) {
    int a = (t >= off) ? sd[t - off] : 0;
    __syncthreads();
    sd[t] += a;
    __syncthreads();
  }
  boff[t] = sd[t] - v;
  if (t == 255) *row_ptr_end = sd[255];
}

__global__ __launch_bounds__(256) void k_scan3(int* __restrict__ row_ptr,
    const int* __restrict__ boff) {
  int i = blockIdx.x * 256 + threadIdx.x;
  if (i < N_NODES) row_ptr[i] += boff[blockIdx.x];
}

// ------ Kernel D: edge weights + scatter packed (col:16 | w:bf16:16) -----------
__global__ __launch_bounds__(256) void k_scatter(const int* __restrict__ ei,
    const float* __restrict__ adj, const float* __restrict__ s_src,
    const float* __restrict__ s_dst, const int* __restrict__ row_ptr,
    int* __restrict__ fill, unsigned* __restrict__ edata) {
  int e = blockIdx.x * 256 + threadIdx.x;
  if (e >= N_EDGES) return;
  int row = ei[e], col = ei[N_EDGES + e];
  int p = row_ptr[row] + atomicAdd(&fill[row], 1);
  float s = s_src[row] + s_dst[col];
  s = (s > 0.f) ? s : 0.2f * s;                 // leaky_relu(0.2)
  float wv = adj[e] / (1.f + __expf(-s));       // sigmoid * adj
  edata[p] = bf16hi(wv) | (unsigned)col;
}

// ------ Kernel E: agg1 edge-streaming, LDS accumulate, -> h1o = relu(agg) bf16 -
// block owns NPB nodes and their whole CSR span; 8 groups of 32 lanes stream
// contiguous edge chunks; register acc flushed to LDS atomicAdd on row change.
__global__ __launch_bounds__(256) void k_agg1(const unsigned* __restrict__ h1u,
    const unsigned* __restrict__ edata, const int* __restrict__ row_ptr,
    unsigned* __restrict__ h1o) {
  __shared__ int rps[NPB + 1];
  __shared__ float accs[NPB][NHID];   // 8 KB
  int t = threadIdx.x;
  int n0 = blockIdx.x * NPB;
  if (t <= NPB) rps[t] = row_ptr[min(n0 + t, N_NODES)];
  for (int i = t; i < NPB * NHID / 4; i += 256)
    ((float4*)&accs[0][0])[i] = make_float4(0.f, 0.f, 0.f, 0.f);
  __syncthreads();
  int e0 = rps[0], e1 = rps[NPB];
  int span = e1 - e0;
  int gid = t >> 5, s = t & 31;
  int chunk = (span + 7) >> 3;
  int es = e0 + gid * chunk;
  int ee = min(es + chunk, e1);
  if (es < ee) {
    // row containing es: r with rps[r] <= es < rps[r+1]
    int lo = 0, hi = NPB - 1;
    while (lo < hi) { int mid = (lo + hi) >> 1; if (rps[mid + 1] <= es) lo = mid + 1; else hi = mid; }
    int r = lo, nxt = rps[r + 1];
    float acc0 = 0.f, acc1 = 0.f;
    int e = es;
    while (e < ee) {
      int m = ee - e; if (m > 8) m = 8;
      unsigned u[8], v[8];
#pragma unroll
      for (int i = 0; i < 8; ++i) if (i < m) u[i] = edata[e + i];
#pragma unroll
      for (int i = 0; i < 8; ++i) if (i < m) v[i] = h1u[(size_t)(u[i] & 0xffffu) * 32 + s];
#pragma unroll
      for (int i = 0; i < 8; ++i) if (i < m) {
        while (e + i >= nxt) {
          atomicAdd(&accs[r][2 * s], acc0);
          atomicAdd(&accs[r][2 * s + 1], acc1);
          acc0 = acc1 = 0.f; ++r; nxt = rps[r + 1];
        }
        float wv = hi16(u[i]);
        acc0 = fmaf(wv, lo16(v[i]), acc0);
        acc1 = fmaf(wv, hi16(v[i]), acc1);
      }
      e += m;
    }
    atomicAdd(&accs[r][2 * s], acc0);
    atomicAdd(&accs[r][2 * s + 1], acc1);
  }
  __syncthreads();
  for (int i = t; i < NPB * 32; i += 256) {
    int n = i >> 5, c = i & 31;
    int gn = n0 + n;
    if (gn < N_NODES)
      h1o[(size_t)gn * 32 + c] =
          packbf(fmaxf(accs[n][2 * c], 0.f), fmaxf(accs[n][2 * c + 1], 0.f));
  }
}

// ------ Kernel G: h2 = h1o @ W2 (bf16 in, bf16 out ushort[40]/row) -------------
__global__ __launch_bounds__(256) void k_h2mm(const unsigned* __restrict__ h1o,
    const float* __restrict__ W2, unsigned short* __restrict__ h2s) {
  __shared__ unsigned xs[H2ROWS * 32];  // [r][ku ^ (r&31)] swizzled, 8 KB
  __shared__ float W2s[NHID * NCLASS];  // 10 KB
  int t = threadIdx.x;
  int R0 = blockIdx.x * H2ROWS;
  for (int i = t; i < NHID * NCLASS; i += 256) W2s[i] = W2[i];
  for (int i = t; i < H2ROWS * 32; i += 256) {
    int r = i >> 5, ku = i & 31;
    int gr = R0 + r;
    unsigned v = (gr < N_NODES) ? h1o[(size_t)gr * 32 + ku] : 0u;
    xs[r * 32 + (ku ^ (r & 31))] = v;
  }
  __syncthreads();
  int q = t & 31, cg = t >> 5;
  int c0 = cg * 5;
  float acc[2][5] = {};
#pragma unroll 8
  for (int ku = 0; ku < 32; ++ku) {
    unsigned ua = xs[q * 32 + (ku ^ q)];
    unsigned ub = xs[(q + 32) * 32 + (ku ^ q)];
    float a0 = lo16(ua), a1 = hi16(ua);
    float b0 = lo16(ub), b1 = hi16(ub);
#pragma unroll
    for (int c = 0; c < 5; ++c) {
      float w0 = W2s[(2 * ku) * NCLASS + c0 + c];
      float w1 = W2s[(2 * ku + 1) * NCLASS + c0 + c];
      acc[0][c] = fmaf(a0, w0, acc[0][c]);
      acc[0][c] = fmaf(a1, w1, acc[0][c]);
      acc[1][c] = fmaf(b0, w0, acc[1][c]);
      acc[1][c] = fmaf(b1, w1, acc[1][c]);
    }
  }
#pragma unroll
  for (int j = 0; j < 2; ++j) {
    int gr = R0 + q + j * 32;
    if (gr < N_NODES) {
#pragma unroll
      for (int c = 0; c < 5; ++c)
        h2s[(size_t)gr * NCLASS + c0 + c] = (unsigned short)(bf16hi(acc[j][c]) >> 16);
    }
  }
}

// ------ Kernel F: agg2 edge-streaming + ReLU + res + LayerNorm -----------------
__global__ __launch_bounds__(256) void k_agg2(const unsigned short* __restrict__ h2s,
    const unsigned* __restrict__ edata, const int* __restrict__ row_ptr,
    const float* __restrict__ res, const float* __restrict__ ln_g,
    const float* __restrict__ ln_b, float* __restrict__ out) {
  __shared__ int rps[NPB + 1];
  __shared__ float accs[NPB][NCLASS];   // 5 KB
  int t = threadIdx.x;
  int n0 = blockIdx.x * NPB;
  if (t <= NPB) rps[t] = row_ptr[min(n0 + t, N_NODES)];
  for (int i = t; i < NPB * NCLASS; i += 256) ((float*)accs)[i] = 0.f;
  __syncthreads();
  int e0 = rps[0], e1 = rps[NPB];
  int span = e1 - e0;
  int gid = t >> 5, s = t & 31;
  int chunk = (span + 7) >> 3;
  int es = e0 + gid * chunk;
  int ee = min(es + chunk, e1);
  bool act = (s < 20);
  if (es < ee) {
    int lo = 0, hi = NPB - 1;
    while (lo < hi) { int mid = (lo + hi) >> 1; if (rps[mid + 1] <= es) lo = mid + 1; else hi = mid; }
    int r = lo, nxt = rps[r + 1];
    float acc0 = 0.f, acc1 = 0.f;
    int e = es;
    while (e < ee) {
      int m = ee - e; if (m > 8) m = 8;
      unsigned u[8], v[8];
#pragma unroll
      for (int i = 0; i < 8; ++i) if (i < m) u[i] = edata[e + i];
#pragma unroll
      for (int i = 0; i < 8; ++i) {
        v[i] = 0u;
        if (i < m && act)
          v[i] = *(const unsigned*)(h2s + (size_t)(u[i] & 0xffffu) * NCLASS + 2 * s);
      }
#pragma unroll
      for (int i = 0; i < 8; ++i) if (i < m) {
        while (e + i >= nxt) {
          if (act) {
            atomicAdd(&accs[r][2 * s], acc0);
            atomicAdd(&accs[r][2 * s + 1], acc1);
          }
          acc0 = acc1 = 0.f; ++r; nxt = rps[r + 1];
        }
        float wv = hi16(u[i]);
        acc0 = fmaf(wv, lo16(v[i]), acc0);
        acc1 = fmaf(wv, hi16(v[i]), acc1);
      }
      e += m;
    }
    if (act) {
      atomicAdd(&accs[r][2 * s], acc0);
      atomicAdd(&accs[r][2 * s + 1], acc1);
    }
  }
  __syncthreads();
  // epilogue: wave handles 8 nodes; lanes 0..39 = classes
  int wave = t >> 6, lane = t & 63;
  for (int k = 0; k < 8; ++k) {
    int n = wave * 8 + k;
    int gn = n0 + n;
    if (gn >= N_NODES) break;
    float y = 0.f;
    if (lane < NCLASS)
      y = fmaxf(accs[n][lane], 0.f) + res[(size_t)gn * NCLASS + lane];
    float s1 = y, s2 = y * y;
#pragma unroll
    for (int off = 1; off < 64; off <<= 1) {
      s1 += __shfl_xor(s1, off);
      s2 += __shfl_xor(s2, off);
    }
    float mu = s1 / (float)NCLASS;
    float var = s2 / (float)NCLASS - mu * mu;
    float inv = rsqrtf(var + LN_EPS);
    if (lane < NCLASS)
      out[(size_t)gn * NCLASS + lane] = (y - mu) * inv * ln_g[lane] + ln_b[lane];
  }
}

// -------------------------------------------------------------------------------
extern "C" void kernel_launch(void* const* d_in, const int* in_sizes, int n_in,
                              void* d_out, int out_size, void* d_ws, size_t ws_size,
                              hipStream_t stream) {
  const float* x     = (const float*)d_in[0];
  const int*   ei    = (const int*)  d_in[1];
  const float* adj   = (const float*)d_in[2];
  const float* W1    = (const float*)d_in[3];
  const float* a1    = (const float*)d_in[4];
  const float* W2    = (const float*)d_in[5];
  const float* res_w = (const float*)d_in[6];
  const float* res_b = (const float*)d_in[7];
  const float* ln_g  = (const float*)d_in[8];
  const float* ln_b  = (const float*)d_in[9];
  float* out = (float*)d_out;

  char* ws = (char*)d_ws;
  size_t off = 0;
  auto alloc = [&](size_t bytes) -> void* {
    void* p = (void*)(ws + off);
    off += (bytes + 255) & ~(size_t)255;
    return p;
  };

  unsigned*       h1u     = (unsigned*)alloc((size_t)N_NODES * 32 * 4);  // bf16x2
  float*          s_src   = (float*)alloc((size_t)N_NODES * 4);
  float*          s_dst   = (float*)alloc((size_t)N_NODES * 4);
  int*            cnt     = (int*)  alloc((size_t)N_NODES * 4);
  int*            row_ptr = (int*)  alloc((size_t)(N_NODES + 1) * 4);
  int*            bsum    = (int*)  alloc(256 * 4);
  int*            boff    = (int*)  alloc(256 * 4);
  unsigned*       edata   = (unsigned*)alloc((size_t)N_EDGES * 4);       // col|w
  unsigned*       h1o     = (unsigned*)alloc((size_t)N_NODES * 32 * 4);  // bf16x2
  unsigned short* h2s     = (unsigned short*)alloc((size_t)N_NODES * NCLASS * 2);
  float*          res     = (float*)alloc((size_t)N_NODES * NCLASS * 4);
  (void)ws_size; (void)in_sizes; (void)n_in; (void)out_size;

  const int NBLK_EDGE = (N_EDGES + 255) / 256;      // 3125
  const int NBLK_SCAN = (N_NODES + 255) / 256;      // 196
  const int NBLK_H1   = (N_NODES + 63) / 64;        // 782
  const int NBLK_RES  = (N_NODES + 127) / 128;      // 391
  const int NBLK_AGG  = (N_NODES + NPB - 1) / NPB;  // 1563
  const int NBLK_H2   = (N_NODES + H2ROWS - 1) / H2ROWS;  // 782

  hipMemsetAsync(cnt, 0, (size_t)N_NODES * 4, stream);
  k_h1mm<<<NBLK_H1, 256, 0, stream>>>(x, W1, a1, h1u, s_src, s_dst);
  k_resmm<<<NBLK_RES, 256, 0, stream>>>(x, res_w, res_b, res);
  k_hist<<<NBLK_EDGE, 256, 0, stream>>>(ei, cnt);
  k_scan1<<<NBLK_SCAN, 256, 0, stream>>>(cnt, row_ptr, bsum);
  k_scan2<<<1, 256, 0, stream>>>(bsum, boff, NBLK_SCAN, row_ptr + N_NODES);
  k_scan3<<<NBLK_SCAN, 256, 0, stream>>>(row_ptr, boff);
  hipMemsetAsync(cnt, 0, (size_t)N_NODES * 4, stream);
  k_scatter<<<NBLK_EDGE, 256, 0, stream>>>(ei, adj, s_src, s_dst, row_ptr, cnt, edata);
  k_agg1<<<NBLK_AGG, 256, 0, stream>>>(h1u, edata, row_ptr, h1o);
  k_h2mm<<<NBLK_H2, 256, 0, stream>>>(h1o, W2, h2s);
  k_agg2<<<NBLK_AGG, 256, 0, stream>>>(h2s, edata, row_ptr, res, ln_g, ln_b, out);
}